// Round 2
// baseline (547.980 us; speedup 1.0000x reference)
//
#include <hip/hip_runtime.h>

// Banded stereo cost volume, all 3 scales fused into ONE launch.
// cost[j,h,x] = sum_c L[c,h,x] * R[c,h,x-j], 0 if x<j. C=32.
// Tile: TJ=128 j x TX=128 x per block, one h. 256 threads, 8x8 reg tile.
// Channels staged in 2 stages of 16 -> 24KB LDS -> 6 blocks/CU.

#define TX 128
#define TJ 128
#define NCS 16   // channels per stage
#define NSTG 2

// XOR swizzle of float4-chunk index within a row to break LDS bank conflicts.
__device__ __forceinline__ int swz64(int q) { return q ^ ((q >> 3) & 7); }
__device__ __forceinline__ int swz32(int q) { return q ^ ((q >> 3) & 3); }

// Block ranges: scale0: [0,2048) nbx=4 nby=2 H=256; scale1: [2048,2304) nbx=2 nby=1;
// scale2: [2304,2368) nbx=1 nby=1.
#define NBLK_TOTAL 2368

__global__ __launch_bounds__(256, 6)
void cost_volume_fused(const float* __restrict__ L0, const float* __restrict__ R0,
                       const float* __restrict__ L1, const float* __restrict__ R1,
                       const float* __restrict__ L2, const float* __restrict__ R2,
                       float* __restrict__ out)
{
    __shared__ float Ls[NCS * TX];        // 8 KB
    __shared__ float Rs[NCS * (TX + TJ)]; // 16 KB

    const int id = blockIdx.x;
    const float* L; const float* R; float* o;
    int H, W, D, bx, by, h;
    if (id < 2048) {            // scale 0: H=256 W=512 D=192
        L = L0; R = R0; o = out;
        H = 256; W = 512; D = 192;
        bx = id & 3; by = (id >> 2) & 1; h = id >> 3;
    } else if (id < 2304) {     // scale 1: H=128 W=256 D=96
        int r = id - 2048;
        L = L1; R = R1; o = out + (size_t)192 * 256 * 512;
        H = 128; W = 256; D = 96;
        bx = r & 1; by = 0; h = r >> 1;
    } else {                    // scale 2: H=64 W=128 D=48
        int r = id - 2304;
        L = L2; R = R2; o = out + (size_t)192 * 256 * 512 + (size_t)96 * 128 * 256;
        H = 64; W = 128; D = 48;
        bx = 0; by = 0; h = r;
    }

    const int x0 = bx * TX;
    const int j0 = by * TJ;
    const int t  = threadIdx.x;
    const int tx = t & 15;
    const int ty = t >> 4;
    const int jbase = j0 + ty * 8;
    const int xb    = x0 + tx * 8;

    // Fully-dead tile (x < j everywhere): store zeros, whole block returns (no barriers hit).
    if (x0 + TX - 1 < j0) {
        const float4 z = make_float4(0.f, 0.f, 0.f, 0.f);
        #pragma unroll
        for (int jj = 0; jj < 8; ++jj) {
            int j = jbase + jj;
            if (j < D) {
                float* p = o + ((size_t)j * H + h) * W + xb;
                *(float4*)(p)     = z;
                *(float4*)(p + 4) = z;
            }
        }
        return;
    }

    const bool active = (jbase < D);
    const size_t HW = (size_t)H * W;
    const float* Lb = L + (size_t)h * W;
    const float* Rb = R + (size_t)h * W;
    const int gbase = x0 - j0 - TJ;   // left edge of R window (may be <0 -> zero pad)

    float acc[8][8];
    #pragma unroll
    for (int jj = 0; jj < 8; ++jj)
        #pragma unroll
        for (int xx = 0; xx < 8; ++xx) acc[jj][xx] = 0.f;

    // c-invariant LDS read offsets
    const int lo0 = 4 * swz32(2 * tx);
    const int lo1 = 4 * swz32(2 * tx + 1);
    const int qr0 = 2 * (tx - ty) + 30;
    const int ro0 = 4 * swz64(qr0 + 0);
    const int ro1 = 4 * swz64(qr0 + 1);
    const int ro2 = 4 * swz64(qr0 + 2);
    const int ro3 = 4 * swz64(qr0 + 3);

    #pragma unroll
    for (int s = 0; s < NSTG; ++s) {
        const int c0 = s * NCS;
        // ---- stage 16 channels into LDS ----
        #pragma unroll
        for (int k = 0; k < 2; ++k) {
            int f = t + k * 256;        // 512 float4 for Ls
            int c = f >> 5, q = f & 31;
            float4 v = *(const float4*)(Lb + (size_t)(c0 + c) * HW + x0 + 4 * q);
            *(float4*)&Ls[c * TX + 4 * swz32(q)] = v;
        }
        #pragma unroll
        for (int k = 0; k < 4; ++k) {
            int f = t + k * 256;        // 1024 float4 for Rs
            int c = f >> 6, q = f & 63;
            int g = gbase + 4 * q;
            float4 v = make_float4(0.f, 0.f, 0.f, 0.f);
            if (g >= 0 && g < W)        // g, W multiples of 4 -> whole float4 in bounds
                v = *(const float4*)(Rb + (size_t)(c0 + c) * HW + g);
            *(float4*)&Rs[c * (TX + TJ) + 4 * swz64(q)] = v;
        }
        __syncthreads();

        if (active) {
            #pragma unroll 2
            for (int c = 0; c < NCS; ++c) {
                const float* Lc = Ls + c * TX;
                const float* Rc = Rs + c * (TX + TJ);
                float l[8], r[16];
                *(float4*)&l[0]  = *(const float4*)(Lc + lo0);
                *(float4*)&l[4]  = *(const float4*)(Lc + lo1);
                *(float4*)&r[0]  = *(const float4*)(Rc + ro0);
                *(float4*)&r[4]  = *(const float4*)(Rc + ro1);
                *(float4*)&r[8]  = *(const float4*)(Rc + ro2);
                *(float4*)&r[12] = *(const float4*)(Rc + ro3);
                #pragma unroll
                for (int jj = 0; jj < 8; ++jj)
                    #pragma unroll
                    for (int xx = 0; xx < 8; ++xx)
                        acc[jj][xx] = fmaf(l[xx], r[xx - jj + 8], acc[jj][xx]);
            }
        }
        if (s + 1 < NSTG) __syncthreads();   // protect LDS before next stage's writes
    }

    if (active) {
        #pragma unroll
        for (int jj = 0; jj < 8; ++jj) {
            int j = jbase + jj;
            if (j < D) {
                float* p = o + ((size_t)j * H + h) * W + xb;
                *(float4*)(p)     = make_float4(acc[jj][0], acc[jj][1], acc[jj][2], acc[jj][3]);
                *(float4*)(p + 4) = make_float4(acc[jj][4], acc[jj][5], acc[jj][6], acc[jj][7]);
            }
        }
    }
}

extern "C" void kernel_launch(void* const* d_in, const int* in_sizes, int n_in,
                              void* d_out, int out_size, void* d_ws, size_t ws_size,
                              hipStream_t stream)
{
    const float* L0 = (const float*)d_in[0];
    const float* R0 = (const float*)d_in[1];
    const float* L1 = (const float*)d_in[2];
    const float* R1 = (const float*)d_in[3];
    const float* L2 = (const float*)d_in[4];
    const float* R2 = (const float*)d_in[5];
    float* out = (float*)d_out;

    cost_volume_fused<<<dim3(NBLK_TOTAL), dim3(256), 0, stream>>>(
        L0, R0, L1, R1, L2, R2, out);
}

// Round 4
// 519.201 us; speedup vs baseline: 1.0554x; 1.0554x over previous
//
#include <hip/hip_runtime.h>

// Banded stereo cost volume, all 3 scales fused into ONE launch.
// cost[j,h,x] = sum_c L[c,h,x] * R[c,h,x-j], 0 if x<j. C=32.
// Tile: TJ=128 j x TX=128 x per block, one h. 256 threads, 8x8 reg tile.
// Channels staged in 2 stages of 16 -> 24KB LDS -> 6 blocks/CU.
// Output stores are NONTEMPORAL (native vec type for the builtin): output rows
// are 512KB apart (same L2 sets); write-allocate caused ~10x HBM write
// amplification in round 2 (WRITE_SIZE 1.10GB vs 115MB ideal).

#define TX 128
#define TJ 128
#define NCS 16   // channels per stage
#define NSTG 2

typedef float vf4 __attribute__((ext_vector_type(4)));  // native vec for nontemporal builtin

// XOR swizzle of float4-chunk index within a row to break LDS bank conflicts.
__device__ __forceinline__ int swz64(int q) { return q ^ ((q >> 3) & 7); }
__device__ __forceinline__ int swz32(int q) { return q ^ ((q >> 3) & 3); }

#define NBLK_TOTAL 2368

__global__ __launch_bounds__(256, 6)
void cost_volume_fused(const float* __restrict__ L0, const float* __restrict__ R0,
                       const float* __restrict__ L1, const float* __restrict__ R1,
                       const float* __restrict__ L2, const float* __restrict__ R2,
                       float* __restrict__ out)
{
    __shared__ float Ls[NCS * TX];        // 8 KB
    __shared__ float Rs[NCS * (TX + TJ)]; // 16 KB

    const int id = blockIdx.x;
    const float* L; const float* R; float* o;
    int H, W, D, bx, by, h;
    if (id < 2048) {            // scale 0: H=256 W=512 D=192
        L = L0; R = R0; o = out;
        H = 256; W = 512; D = 192;
        bx = id & 3; by = (id >> 2) & 1; h = id >> 3;
    } else if (id < 2304) {     // scale 1: H=128 W=256 D=96
        int r = id - 2048;
        L = L1; R = R1; o = out + (size_t)192 * 256 * 512;
        H = 128; W = 256; D = 96;
        bx = r & 1; by = 0; h = r >> 1;
    } else {                    // scale 2: H=64 W=128 D=48
        int r = id - 2304;
        L = L2; R = R2; o = out + (size_t)192 * 256 * 512 + (size_t)96 * 128 * 256;
        H = 64; W = 128; D = 48;
        bx = 0; by = 0; h = r;
    }

    const int x0 = bx * TX;
    const int j0 = by * TJ;
    const int t  = threadIdx.x;
    const int tx = t & 15;
    const int ty = t >> 4;
    const int jbase = j0 + ty * 8;
    const int xb    = x0 + tx * 8;

    // Fully-dead tile (x < j everywhere): store zeros, whole block returns.
    if (x0 + TX - 1 < j0) {
        const vf4 z = (vf4)(0.f);
        #pragma unroll
        for (int jj = 0; jj < 8; ++jj) {
            int j = jbase + jj;
            if (j < D) {
                float* p = o + ((size_t)j * H + h) * W + xb;
                __builtin_nontemporal_store(z, (vf4*)(p));
                __builtin_nontemporal_store(z, (vf4*)(p + 4));
            }
        }
        return;
    }

    const bool active = (jbase < D);
    const size_t HW = (size_t)H * W;
    const float* Lb = L + (size_t)h * W;
    const float* Rb = R + (size_t)h * W;
    const int gbase = x0 - j0 - TJ;   // left edge of R window (may be <0 -> zero pad)

    float acc[8][8];
    #pragma unroll
    for (int jj = 0; jj < 8; ++jj)
        #pragma unroll
        for (int xx = 0; xx < 8; ++xx) acc[jj][xx] = 0.f;

    // c-invariant LDS read offsets
    const int lo0 = 4 * swz32(2 * tx);
    const int lo1 = 4 * swz32(2 * tx + 1);
    const int qr0 = 2 * (tx - ty) + 30;
    const int ro0 = 4 * swz64(qr0 + 0);
    const int ro1 = 4 * swz64(qr0 + 1);
    const int ro2 = 4 * swz64(qr0 + 2);
    const int ro3 = 4 * swz64(qr0 + 3);

    #pragma unroll
    for (int s = 0; s < NSTG; ++s) {
        const int c0 = s * NCS;
        // ---- stage 16 channels into LDS ----
        #pragma unroll
        for (int k = 0; k < 2; ++k) {
            int f = t + k * 256;        // 512 float4 for Ls
            int c = f >> 5, q = f & 31;
            vf4 v = *(const vf4*)(Lb + (size_t)(c0 + c) * HW + x0 + 4 * q);
            *(vf4*)&Ls[c * TX + 4 * swz32(q)] = v;
        }
        #pragma unroll
        for (int k = 0; k < 4; ++k) {
            int f = t + k * 256;        // 1024 float4 for Rs
            int c = f >> 6, q = f & 63;
            int g = gbase + 4 * q;
            vf4 v = (vf4)(0.f);
            if (g >= 0 && g < W)        // g, W multiples of 4 -> whole float4 in bounds
                v = *(const vf4*)(Rb + (size_t)(c0 + c) * HW + g);
            *(vf4*)&Rs[c * (TX + TJ) + 4 * swz64(q)] = v;
        }
        __syncthreads();

        if (active) {
            #pragma unroll 2
            for (int c = 0; c < NCS; ++c) {
                const float* Lc = Ls + c * TX;
                const float* Rc = Rs + c * (TX + TJ);
                float l[8], r[16];
                *(vf4*)&l[0]  = *(const vf4*)(Lc + lo0);
                *(vf4*)&l[4]  = *(const vf4*)(Lc + lo1);
                *(vf4*)&r[0]  = *(const vf4*)(Rc + ro0);
                *(vf4*)&r[4]  = *(const vf4*)(Rc + ro1);
                *(vf4*)&r[8]  = *(const vf4*)(Rc + ro2);
                *(vf4*)&r[12] = *(const vf4*)(Rc + ro3);
                #pragma unroll
                for (int jj = 0; jj < 8; ++jj)
                    #pragma unroll
                    for (int xx = 0; xx < 8; ++xx)
                        acc[jj][xx] = fmaf(l[xx], r[xx - jj + 8], acc[jj][xx]);
            }
        }
        if (s + 1 < NSTG) __syncthreads();   // protect LDS before next stage's writes
    }

    if (active) {
        #pragma unroll
        for (int jj = 0; jj < 8; ++jj) {
            int j = jbase + jj;
            if (j < D) {
                float* p = o + ((size_t)j * H + h) * W + xb;
                vf4 v0 = {acc[jj][0], acc[jj][1], acc[jj][2], acc[jj][3]};
                vf4 v1 = {acc[jj][4], acc[jj][5], acc[jj][6], acc[jj][7]};
                __builtin_nontemporal_store(v0, (vf4*)(p));
                __builtin_nontemporal_store(v1, (vf4*)(p + 4));
            }
        }
    }
}

extern "C" void kernel_launch(void* const* d_in, const int* in_sizes, int n_in,
                              void* d_out, int out_size, void* d_ws, size_t ws_size,
                              hipStream_t stream)
{
    const float* L0 = (const float*)d_in[0];
    const float* R0 = (const float*)d_in[1];
    const float* L1 = (const float*)d_in[2];
    const float* R1 = (const float*)d_in[3];
    const float* L2 = (const float*)d_in[4];
    const float* R2 = (const float*)d_in[5];
    float* out = (float*)d_out;

    cost_volume_fused<<<dim3(NBLK_TOTAL), dim3(256), 0, stream>>>(
        L0, R0, L1, R1, L2, R2, out);
}

// Round 5
// 183.451 us; speedup vs baseline: 2.9871x; 2.8302x over previous
//
#include <hip/hip_runtime.h>

// Banded stereo cost volume, all 3 scales fused into ONE launch.
// cost[j,h,x] = sum_c L[c,h,x] * R[c,h,x-j], 0 if x<j. C=32.
// Tile: TJ=128 j x TX=128 x per block, one h. 256 threads.
// Thread owns 8 j-rows and TWO 4-float x-runs 64 apart, so every global
// store instruction writes 256 B fully contiguous (2 whole 128-B lines):
// rounds 2/4 showed half-line strided stores caused ~8.6x HBM write
// amplification (WRITE_SIZE 985 MB vs 115 MB ideal) via L2 set thrash.

#define TX 128
#define TJ 128
#define NCS 16   // channels per stage
#define NSTG 2

typedef float vf4 __attribute__((ext_vector_type(4)));

// XOR swizzle of float4-chunk index within a row to break LDS bank conflicts.
__device__ __forceinline__ int swz64(int q) { return q ^ ((q >> 3) & 7); }
__device__ __forceinline__ int swz32(int q) { return q ^ ((q >> 3) & 3); }

#define NBLK_TOTAL 2368

__global__ __launch_bounds__(256, 4)
void cost_volume_fused(const float* __restrict__ L0, const float* __restrict__ R0,
                       const float* __restrict__ L1, const float* __restrict__ R1,
                       const float* __restrict__ L2, const float* __restrict__ R2,
                       float* __restrict__ out)
{
    __shared__ float Ls[NCS * TX];        // 8 KB
    __shared__ float Rs[NCS * (TX + TJ)]; // 16 KB

    const int id = blockIdx.x;
    const float* L; const float* R; float* o;
    int H, W, D, bx, by, h;
    if (id < 2048) {            // scale 0: H=256 W=512 D=192
        L = L0; R = R0; o = out;
        H = 256; W = 512; D = 192;
        bx = id & 3; by = (id >> 2) & 1; h = id >> 3;
    } else if (id < 2304) {     // scale 1: H=128 W=256 D=96
        int r = id - 2048;
        L = L1; R = R1; o = out + (size_t)192 * 256 * 512;
        H = 128; W = 256; D = 96;
        bx = r & 1; by = 0; h = r >> 1;
    } else {                    // scale 2: H=64 W=128 D=48
        int r = id - 2304;
        L = L2; R = R2; o = out + (size_t)192 * 256 * 512 + (size_t)96 * 128 * 256;
        H = 64; W = 128; D = 48;
        bx = 0; by = 0; h = r;
    }

    const int x0 = bx * TX;
    const int j0 = by * TJ;
    const int t  = threadIdx.x;
    const int tx = t & 15;
    const int ty = t >> 4;
    const int jbase = j0 + ty * 8;

    // Fully-dead tile (x < j everywhere): store zeros, whole block returns.
    if (x0 + TX - 1 < j0) {
        const vf4 z = (vf4)(0.f);
        #pragma unroll
        for (int jj = 0; jj < 8; ++jj) {
            int j = jbase + jj;
            if (j < D) {
                float* p = o + ((size_t)j * H + h) * W + x0;
                __builtin_nontemporal_store(z, (vf4*)(p + 4 * tx));
                __builtin_nontemporal_store(z, (vf4*)(p + 64 + 4 * tx));
            }
        }
        return;
    }

    const bool active = (jbase < D);
    const size_t HW = (size_t)H * W;
    const float* Lb = L + (size_t)h * W;
    const float* Rb = R + (size_t)h * W;
    const int gbase = x0 - j0 - TJ;   // left edge of R window (may be <0 -> zero pad)

    float acc[8][8];
    #pragma unroll
    for (int jj = 0; jj < 8; ++jj)
        #pragma unroll
        for (int xx = 0; xx < 8; ++xx) acc[jj][xx] = 0.f;

    // c-invariant LDS read offsets.
    // L: x-run A = chunk tx (floats 4tx..4tx+3), run B = chunk tx+16.
    // R: logical float idx = xlocal - jlocal + 128; run A needs floats
    //    [4tA+121, 4tA+131] (tA = tx-2ty) -> chunks tA+30..32; run B: +16 chunks.
    const int loA = 4 * swz32(tx);
    const int loB = 4 * swz32(tx + 16);
    const int tA  = tx - 2 * ty;
    const int roA0 = 4 * swz64(tA + 30);
    const int roA1 = 4 * swz64(tA + 31);
    const int roA2 = 4 * swz64(tA + 32);
    const int roB0 = 4 * swz64(tA + 46);
    const int roB1 = 4 * swz64(tA + 47);
    const int roB2 = 4 * swz64(tA + 48);

    #pragma unroll
    for (int s = 0; s < NSTG; ++s) {
        const int c0 = s * NCS;
        // ---- stage 16 channels into LDS ----
        #pragma unroll
        for (int k = 0; k < 2; ++k) {
            int f = t + k * 256;        // 512 float4 for Ls
            int c = f >> 5, q = f & 31;
            vf4 v = *(const vf4*)(Lb + (size_t)(c0 + c) * HW + x0 + 4 * q);
            *(vf4*)&Ls[c * TX + 4 * swz32(q)] = v;
        }
        #pragma unroll
        for (int k = 0; k < 4; ++k) {
            int f = t + k * 256;        // 1024 float4 for Rs
            int c = f >> 6, q = f & 63;
            int g = gbase + 4 * q;
            vf4 v = (vf4)(0.f);
            if (g >= 0 && g < W)        // g, W multiples of 4 -> whole float4 in bounds
                v = *(const vf4*)(Rb + (size_t)(c0 + c) * HW + g);
            *(vf4*)&Rs[c * (TX + TJ) + 4 * swz64(q)] = v;
        }
        __syncthreads();

        if (active) {
            #pragma unroll 1
            for (int c = 0; c < NCS; ++c) {
                const float* Lc = Ls + c * TX;
                const float* Rc = Rs + c * (TX + TJ);
                float lA[4], lB[4], rA[12], rB[12];
                *(vf4*)&lA[0] = *(const vf4*)(Lc + loA);
                *(vf4*)&lB[0] = *(const vf4*)(Lc + loB);
                *(vf4*)&rA[0] = *(const vf4*)(Rc + roA0);
                *(vf4*)&rA[4] = *(const vf4*)(Rc + roA1);
                *(vf4*)&rA[8] = *(const vf4*)(Rc + roA2);
                *(vf4*)&rB[0] = *(const vf4*)(Rc + roB0);
                *(vf4*)&rB[4] = *(const vf4*)(Rc + roB1);
                *(vf4*)&rB[8] = *(const vf4*)(Rc + roB2);
                // r-index: logical float (4tA+120) + k ; needed = 8 + i - jj
                #pragma unroll
                for (int jj = 0; jj < 8; ++jj)
                    #pragma unroll
                    for (int i = 0; i < 4; ++i) {
                        acc[jj][i]     = fmaf(lA[i], rA[8 + i - jj], acc[jj][i]);
                        acc[jj][4 + i] = fmaf(lB[i], rB[8 + i - jj], acc[jj][4 + i]);
                    }
            }
        }
        if (s + 1 < NSTG) __syncthreads();   // protect LDS before next stage's writes
    }

    if (active) {
        #pragma unroll
        for (int jj = 0; jj < 8; ++jj) {
            int j = jbase + jj;
            if (j < D) {
                float* p = o + ((size_t)j * H + h) * W + x0;
                vf4 va = {acc[jj][0], acc[jj][1], acc[jj][2], acc[jj][3]};
                vf4 vb = {acc[jj][4], acc[jj][5], acc[jj][6], acc[jj][7]};
                __builtin_nontemporal_store(va, (vf4*)(p + 4 * tx));
                __builtin_nontemporal_store(vb, (vf4*)(p + 64 + 4 * tx));
            }
        }
    }
}

extern "C" void kernel_launch(void* const* d_in, const int* in_sizes, int n_in,
                              void* d_out, int out_size, void* d_ws, size_t ws_size,
                              hipStream_t stream)
{
    const float* L0 = (const float*)d_in[0];
    const float* R0 = (const float*)d_in[1];
    const float* L1 = (const float*)d_in[2];
    const float* R1 = (const float*)d_in[3];
    const float* L2 = (const float*)d_in[4];
    const float* R2 = (const float*)d_in[5];
    float* out = (float*)d_out;

    cost_volume_fused<<<dim3(NBLK_TOTAL), dim3(256), 0, stream>>>(
        L0, R0, L1, R1, L2, R2, out);
}